// Round 2
// baseline (18007.079 us; speedup 1.0000x reference)
//
#include <hip/hip_runtime.h>
#include <hip/hip_bf16.h>
#include <cstdint>
#include <cstddef>

// T=256, B=64, IN=2048, H=1024, L=3, D=2
// Phased: S=16 timesteps per phase, 16 phases/layer.
// GX region: 2048 local rows (fwd 0..1023, bwd 1024..2047) x 6144 fp32 = 48 MiB.

typedef short short8 __attribute__((ext_vector_type(8)));
typedef float f32x4 __attribute__((ext_vector_type(4)));

__device__ __forceinline__ void async16(const void* g, void* l) {
  __builtin_amdgcn_global_load_lds(
      (const __attribute__((address_space(1))) unsigned int*)g,
      (__attribute__((address_space(3))) unsigned int*)l,
      16, 0, 0);
}

// ---------------- fp32 -> bf16 convert (grid-stride) ----------------
__global__ void f2b(const float* __restrict__ src, __hip_bfloat16* __restrict__ dst, int n) {
  int i = blockIdx.x * blockDim.x + threadIdx.x;
  int stride = gridDim.x * blockDim.x;
  for (; i < n; i += stride) dst[i] = __float2bfloat16(src[i]);
}

// ---------------- bf16 GEMM (phased): C[2048][6144] = A[rows][2048] @ Bw[6144][2048]^T + bias
// Local rows [0,1024) map to global A rows rowBase0+r ; [1024,2048) -> rowBase1+(r-1024).
__global__ __launch_bounds__(256) void gemm_bias_bt(
    const __hip_bfloat16* __restrict__ A,
    const __hip_bfloat16* __restrict__ Bw,
    const float* __restrict__ bias,
    float* __restrict__ C,
    int rowBase0, int rowBase1) {
  __shared__ short As[128 * 32];
  __shared__ short Bs[128 * 32];
  const int tid = threadIdx.x;
  const int lane = tid & 63;
  const int wid = tid >> 6;
  const int m0 = blockIdx.x * 128;             // local row base (0..1920)
  const int n0 = blockIdx.y * 128;
  const int grow = (m0 < 1024) ? (rowBase0 + m0) : (rowBase1 + (m0 - 1024));
  const int wm = wid & 1, wn = wid >> 1;

  f32x4 acc[4][4] = {};

  const short* Ag = (const short*)A;
  const short* Bg = (const short*)Bw;
  const int srow = wid * 16 + (lane >> 2);
  const int sk = (lane & 3) * 8;

  for (int kb = 0; kb < 2048; kb += 32) {
    async16(Ag + (size_t)(grow + srow) * 2048 + kb + sk, &As[wid * 512]);
    async16(Ag + (size_t)(grow + srow + 64) * 2048 + kb + sk, &As[wid * 512 + 2048]);
    async16(Bg + (size_t)(n0 + srow) * 2048 + kb + sk, &Bs[wid * 512]);
    async16(Bg + (size_t)(n0 + srow + 64) * 2048 + kb + sk, &Bs[wid * 512 + 2048]);
    __syncthreads();

    const int q = (lane >> 4) * 8;
    const int rl = lane & 15;
    short8 a[4], b[4];
#pragma unroll
    for (int i = 0; i < 4; i++) a[i] = *(const short8*)&As[(wm * 64 + i * 16 + rl) * 32 + q];
#pragma unroll
    for (int j = 0; j < 4; j++) b[j] = *(const short8*)&Bs[(wn * 64 + j * 16 + rl) * 32 + q];
#pragma unroll
    for (int i = 0; i < 4; i++)
#pragma unroll
      for (int j = 0; j < 4; j++)
        acc[i][j] = __builtin_amdgcn_mfma_f32_16x16x32_bf16(a[i], b[j], acc[i][j], 0, 0, 0);
    __syncthreads();
  }

  const int rl = lane & 15;
  const int rq = lane >> 4;
#pragma unroll
  for (int i = 0; i < 4; i++) {
#pragma unroll
    for (int j = 0; j < 4; j++) {
      int col = n0 + wn * 64 + j * 16 + rl;
      float bv = bias[col];
#pragma unroll
      for (int r = 0; r < 4; r++) {
        int row = m0 + wm * 64 + i * 16 + rq * 4 + r;   // local row
        C[(size_t)row * 6144 + col] = acc[i][j][r] + bv;
      }
    }
  }
}

// ---------------- fused GRU step (both directions) ----------------
__global__ __launch_bounds__(256) void gru_step(
    const __hip_bfloat16* __restrict__ Whhb,  // [2*3072][1024] bf16 (current layer)
    const float* __restrict__ bhh,            // [6144]
    const float* __restrict__ GX,             // [2048][6144] phase-local
    const __hip_bfloat16* __restrict__ hb_in, // [2][64][1024]
    const float* __restrict__ hf_in,
    __hip_bfloat16* __restrict__ hb_out,
    float* __restrict__ hf_out,
    __hip_bfloat16* __restrict__ Y,           // [256][64][2048] or unused
    float* __restrict__ outF,                 // out + l*131072
    int t, int gxFwd, int gxBwd, int writeY, int lastStep) {
  const int lane = threadIdx.x & 63;
  const int wid = threadIdx.x >> 6;
  const int wg = blockIdx.x * 4 + wid;   // 0..511
  const int d = wg >> 8;
  const int rem = wg & 255;
  const int mt = rem & 3;
  const int ct = rem >> 2;
  const int tau = d ? (255 - t) : t;

  const int rl = lane & 15;
  const int q = (lane >> 4) * 8;

  const short* hbase = (const short*)hb_in + d * 65536 + (mt * 16 + rl) * 1024;
  const short* wbase = (const short*)Whhb + (size_t)d * 3145728 + (size_t)(ct * 16 + rl) * 1024;

  f32x4 aR = {}, aZ = {}, aN = {};
#pragma unroll 4
  for (int k = 0; k < 1024; k += 32) {
    short8 av = *(const short8*)&hbase[k + q];
    short8 b0 = *(const short8*)&wbase[k + q];
    short8 b1 = *(const short8*)&wbase[1048576 + k + q];
    short8 b2 = *(const short8*)&wbase[2097152 + k + q];
    aR = __builtin_amdgcn_mfma_f32_16x16x32_bf16(av, b0, aR, 0, 0, 0);
    aZ = __builtin_amdgcn_mfma_f32_16x16x32_bf16(av, b1, aZ, 0, 0, 0);
    aN = __builtin_amdgcn_mfma_f32_16x16x32_bf16(av, b2, aN, 0, 0, 0);
  }

  const int col = lane & 15;
  const int rq = lane >> 4;
  const int c = ct * 16 + col;
  const float bR = bhh[d * 3072 + c];
  const float bZ = bhh[d * 3072 + 1024 + c];
  const float bN = bhh[d * 3072 + 2048 + c];
  const int gxRowBase = d ? gxBwd : gxFwd;

#pragma unroll
  for (int r = 0; r < 4; r++) {
    const int b = mt * 16 + rq * 4 + r;
    const size_t gxoff = (size_t)(gxRowBase + b) * 6144 + d * 3072 + c;
    const float ghR = aR[r] + bR;
    const float ghZ = aZ[r] + bZ;
    const float ghN = aN[r] + bN;
    const float xr = GX[gxoff];
    const float xz = GX[gxoff + 1024];
    const float xn = GX[gxoff + 2048];
    const float rg = 1.f / (1.f + __expf(-(xr + ghR)));
    const float zg = 1.f / (1.f + __expf(-(xz + ghZ)));
    const float nv = xn + rg * ghN;
    const float ax = fabsf(nv);
    const float e = __expf(-2.f * ax);
    float th = (1.f - e) / (1.f + e);
    th = copysignf(th, nv);
    const float hp = hf_in[d * 65536 + b * 1024 + c];
    const float hn = th + zg * (hp - th);
    const int hoff = d * 65536 + b * 1024 + c;
    hf_out[hoff] = hn;
    hb_out[hoff] = __float2bfloat16(hn);
    if (writeY) Y[(size_t)(tau * 64 + b) * 2048 + d * 1024 + c] = __float2bfloat16(hn);
    if (lastStep) outF[hoff] = hn;
  }
}

// ---------------- launch ----------------
extern "C" void kernel_launch(void* const* d_in, const int* in_sizes, int n_in,
                              void* d_out, int out_size, void* d_ws, size_t ws_size,
                              hipStream_t stream) {
  (void)in_sizes; (void)n_in; (void)out_size; (void)ws_size;
  const float* x    = (const float*)d_in[0];
  const float* h0   = (const float*)d_in[1];
  const float* w_ih = (const float*)d_in[2];
  const float* w_hh = (const float*)d_in[3];
  const float* b_ih = (const float*)d_in[4];
  const float* b_hh = (const float*)d_in[5];
  float* out = (float*)d_out;

  // Workspace layout (~213.5 MiB total)
  char* p = (char*)d_ws;
  __hip_bfloat16* SEQA = (__hip_bfloat16*)p; p += (size_t)16384 * 2048 * 2;   // 64 MiB
  __hip_bfloat16* SEQB = (__hip_bfloat16*)p; p += (size_t)16384 * 2048 * 2;   // 64 MiB
  float* GX            = (float*)p;          p += (size_t)2048 * 6144 * 4;    // 48 MiB
  __hip_bfloat16* Wihb = (__hip_bfloat16*)p; p += (size_t)6144 * 2048 * 2;    // 24 MiB
  __hip_bfloat16* Whhb = (__hip_bfloat16*)p; p += (size_t)6144 * 1024 * 2;    // 12 MiB
  __hip_bfloat16* HB   = (__hip_bfloat16*)p; p += (size_t)2 * 131072 * 2;     // 512 KiB
  float* HF            = (float*)p;          p += (size_t)2 * 131072 * 4;     // 1 MiB

  f2b<<<2048, 256, 0, stream>>>(x, SEQA, 16384 * 2048);

  for (int l = 0; l < 3; ++l) {
    const __hip_bfloat16* In = (l & 1) ? SEQB : SEQA;
    __hip_bfloat16* Yout = (l & 1) ? SEQA : SEQB;   // unused for l==2
    const int writeY = (l < 2) ? 1 : 0;

    f2b<<<2048, 256, 0, stream>>>(w_ih + (size_t)l * 6144 * 2048, Wihb, 6144 * 2048);
    f2b<<<2048, 256, 0, stream>>>(w_hh + (size_t)l * 6144 * 1024, Whhb, 6144 * 1024);
    f2b<<<64, 256, 0, stream>>>(h0 + (size_t)l * 131072, HB, 131072);

    for (int ph = 0; ph < 16; ++ph) {
      const int rowBase0 = ph * 1024;            // fwd t in [16p, 16p+16)
      const int rowBase1 = 15360 - ph * 1024;    // bwd tau in [240-16p, 256-16p)
      gemm_bias_bt<<<dim3(16, 48), 256, 0, stream>>>(
          In, Wihb, b_ih + l * 6144, GX, rowBase0, rowBase1);

      for (int u = 0; u < 16; ++u) {
        const int t = ph * 16 + u;
        const int gxFwd = u * 64;
        const int gxBwd = 1024 + (15 - u) * 64;
        const float* hf_in = (t == 0) ? (h0 + (size_t)l * 131072) : (HF + (size_t)(t & 1) * 131072);
        float* hf_out = HF + (size_t)((t + 1) & 1) * 131072;
        const __hip_bfloat16* hb_in = HB + (size_t)(t & 1) * 131072;
        __hip_bfloat16* hb_out = HB + (size_t)((t + 1) & 1) * 131072;
        gru_step<<<128, 256, 0, stream>>>(
            Whhb, b_hh + l * 6144, GX,
            hb_in, hf_in, hb_out, hf_out, Yout,
            out + (size_t)l * 131072, t, gxFwd, gxBwd, writeY, (t == 255) ? 1 : 0);
      }
    }
  }
}

// Round 3
// 10481.280 us; speedup vs baseline: 1.7180x; 1.7180x over previous
//
#include <hip/hip_runtime.h>
#include <hip/hip_bf16.h>
#include <cstdint>
#include <cstddef>

// T=256, B=64, IN=2048, H=1024, L=3, D=2
// Phased: 16 timesteps/phase, 16 phases/layer.
// GX: [2048][3072] fp32 (fwd local rows 0..1023 = cols 0..3071 of fwd gates;
//     bwd local rows 1024..2047 = cols of bwd gates). 24 MiB.

typedef short short8 __attribute__((ext_vector_type(8)));
typedef float f32x4 __attribute__((ext_vector_type(4)));

__device__ __forceinline__ void async16(const void* g, void* l) {
  __builtin_amdgcn_global_load_lds(
      (const __attribute__((address_space(1))) unsigned int*)g,
      (__attribute__((address_space(3))) unsigned int*)l,
      16, 0, 0);
}

// ---------------- fp32 -> bf16 convert (grid-stride) ----------------
__global__ void f2b(const float* __restrict__ src, __hip_bfloat16* __restrict__ dst, int n) {
  int i = blockIdx.x * blockDim.x + threadIdx.x;
  int stride = gridDim.x * blockDim.x;
  for (; i < n; i += stride) dst[i] = __float2bfloat16(src[i]);
}

// ---------------- bf16 GEMM (phased, halved): C[2048][3072] ----------------
// local row r<1024: gx[fwd t rows] uses weight rows [0,3072)
// local row r>=1024: gx[bwd] uses weight rows [3072,6144)
__global__ __launch_bounds__(256) void gemm_bias_bt(
    const __hip_bfloat16* __restrict__ A,
    const __hip_bfloat16* __restrict__ Bw,
    const float* __restrict__ bias,
    float* __restrict__ C,
    int rowBase0, int rowBase1) {
  __shared__ short As[128 * 32];
  __shared__ short Bs[128 * 32];
  const int tid = threadIdx.x;
  const int lane = tid & 63;
  const int wid = tid >> 6;
  const int m0 = blockIdx.x * 128;             // local row base (0..1920)
  const int n0 = blockIdx.y * 128;             // [0,3072)
  const int grow = (m0 < 1024) ? (rowBase0 + m0) : (rowBase1 + (m0 - 1024));
  const int cb = (m0 < 1024) ? 0 : 3072;       // weight/bias column-group base
  const int wm = wid & 1, wn = wid >> 1;

  f32x4 acc[4][4] = {};

  const short* Ag = (const short*)A;
  const short* Bg = (const short*)Bw + (size_t)cb * 2048;
  const int srow = wid * 16 + (lane >> 2);
  const int sk = (lane & 3) * 8;

  for (int kb = 0; kb < 2048; kb += 32) {
    async16(Ag + (size_t)(grow + srow) * 2048 + kb + sk, &As[wid * 512]);
    async16(Ag + (size_t)(grow + srow + 64) * 2048 + kb + sk, &As[wid * 512 + 2048]);
    async16(Bg + (size_t)(n0 + srow) * 2048 + kb + sk, &Bs[wid * 512]);
    async16(Bg + (size_t)(n0 + srow + 64) * 2048 + kb + sk, &Bs[wid * 512 + 2048]);
    __syncthreads();

    const int q = (lane >> 4) * 8;
    const int rl = lane & 15;
    short8 a[4], b[4];
#pragma unroll
    for (int i = 0; i < 4; i++) a[i] = *(const short8*)&As[(wm * 64 + i * 16 + rl) * 32 + q];
#pragma unroll
    for (int j = 0; j < 4; j++) b[j] = *(const short8*)&Bs[(wn * 64 + j * 16 + rl) * 32 + q];
#pragma unroll
    for (int i = 0; i < 4; i++)
#pragma unroll
      for (int j = 0; j < 4; j++)
        acc[i][j] = __builtin_amdgcn_mfma_f32_16x16x32_bf16(a[i], b[j], acc[i][j], 0, 0, 0);
    __syncthreads();
  }

  const int rl = lane & 15;
  const int rq = lane >> 4;
#pragma unroll
  for (int i = 0; i < 4; i++) {
#pragma unroll
    for (int j = 0; j < 4; j++) {
      int col = n0 + wn * 64 + j * 16 + rl;     // [0,3072)
      float bv = bias[cb + col];
#pragma unroll
      for (int r = 0; r < 4; r++) {
        int row = m0 + wm * 64 + i * 16 + rq * 4 + r;
        C[(size_t)row * 3072 + col] = acc[i][j][r] + bv;
      }
    }
  }
}

// ---------------- fused GRU step (both directions) ----------------
// 256 blocks: blockIdx.x = mh*128 + d*64 + ct  (mh,d strides ≡0 mod 8 → same XCD
// for both mh copies of a (d,ct) weight slice → L2-resident across steps).
// 4 waves = (kh, mtl): wave computes all 3 gates for rows (mh*2+mtl)*16..+16,
// cols ct*16..+16, k in [kh*512, kh*512+512). kh halves reduce via LDS.
__global__ __launch_bounds__(256) void gru_step(
    const __hip_bfloat16* __restrict__ Whhb,  // [2*3072][1024] bf16
    const float* __restrict__ bhh,            // [6144]
    const float* __restrict__ GX,             // [2048][3072]
    const __hip_bfloat16* __restrict__ hb_in, // [2][64][1024]
    const float* __restrict__ hf_in,
    __hip_bfloat16* __restrict__ hb_out,
    float* __restrict__ hf_out,
    __hip_bfloat16* __restrict__ Y,           // [256][64][2048]
    float* __restrict__ outF,
    int t, int gxFwd, int gxBwd, int writeY, int lastStep) {
  __shared__ float P[2][3][16][17];

  const int bid = blockIdx.x;
  const int mh = bid >> 7;
  const int d = (bid >> 6) & 1;
  const int ct = bid & 63;
  const int lane = threadIdx.x & 63;
  const int wid = threadIdx.x >> 6;
  const int kh = wid >> 1;
  const int mtl = wid & 1;
  const int mt = mh * 2 + mtl;

  const int rl = lane & 15;
  const int rq = lane >> 4;
  const int q = rq * 8;

  // epilogue prefetch (kh==1 waves only; wave-uniform branch)
  float gxr[4], gxz[4], gxn[4], hp[4];
  float bR = 0.f, bZ = 0.f, bN = 0.f;
  const int c = ct * 16 + rl;
  if (kh == 1) {
    bR = bhh[d * 3072 + c];
    bZ = bhh[d * 3072 + 1024 + c];
    bN = bhh[d * 3072 + 2048 + c];
    const int gxBase = d ? gxBwd : gxFwd;
#pragma unroll
    for (int r = 0; r < 4; r++) {
      const int b = mt * 16 + rq * 4 + r;
      const float* g = GX + (size_t)(gxBase + b) * 3072 + c;
      gxr[r] = g[0];
      gxz[r] = g[1024];
      gxn[r] = g[2048];
      hp[r] = hf_in[d * 65536 + b * 1024 + c];
    }
  }

  const short* hrow = (const short*)hb_in + d * 65536 + (mt * 16 + rl) * 1024 + kh * 512 + q;
  const short* wr = (const short*)Whhb + (size_t)(d * 3072 + ct * 16 + rl) * 1024 + kh * 512 + q;

  f32x4 aR = {}, aZ = {}, aN = {};
#pragma unroll
  for (int ki = 0; ki < 16; ki++) {
    const int off = ki * 32;
    short8 av = *(const short8*)&hrow[off];
    short8 b0 = *(const short8*)&wr[off];
    short8 b1 = *(const short8*)&wr[off + 1048576];
    short8 b2 = *(const short8*)&wr[off + 2097152];
    aR = __builtin_amdgcn_mfma_f32_16x16x32_bf16(av, b0, aR, 0, 0, 0);
    aZ = __builtin_amdgcn_mfma_f32_16x16x32_bf16(av, b1, aZ, 0, 0, 0);
    aN = __builtin_amdgcn_mfma_f32_16x16x32_bf16(av, b2, aN, 0, 0, 0);
  }

  if (kh == 0) {
#pragma unroll
    for (int r = 0; r < 4; r++) {
      P[mtl][0][rq * 4 + r][rl] = aR[r];
      P[mtl][1][rq * 4 + r][rl] = aZ[r];
      P[mtl][2][rq * 4 + r][rl] = aN[r];
    }
  }
  __syncthreads();

  if (kh == 1) {
    const int tau = d ? (255 - t) : t;
#pragma unroll
    for (int r = 0; r < 4; r++) {
      const int row = rq * 4 + r;
      const int b = mt * 16 + row;
      const float ghR = aR[r] + P[mtl][0][row][rl] + bR;
      const float ghZ = aZ[r] + P[mtl][1][row][rl] + bZ;
      const float ghN = aN[r] + P[mtl][2][row][rl] + bN;
      const float rg = 1.f / (1.f + __expf(-(gxr[r] + ghR)));
      const float zg = 1.f / (1.f + __expf(-(gxz[r] + ghZ)));
      const float nv = gxn[r] + rg * ghN;
      const float ax = fabsf(nv);
      const float e = __expf(-2.f * ax);
      float th = (1.f - e) / (1.f + e);
      th = copysignf(th, nv);
      const float hn = th + zg * (hp[r] - th);
      const int hoff = d * 65536 + b * 1024 + c;
      hf_out[hoff] = hn;
      hb_out[hoff] = __float2bfloat16(hn);
      if (writeY) Y[(size_t)(tau * 64 + b) * 2048 + d * 1024 + c] = __float2bfloat16(hn);
      if (lastStep) outF[hoff] = hn;
    }
  }
}

// ---------------- launch ----------------
extern "C" void kernel_launch(void* const* d_in, const int* in_sizes, int n_in,
                              void* d_out, int out_size, void* d_ws, size_t ws_size,
                              hipStream_t stream) {
  (void)in_sizes; (void)n_in; (void)out_size; (void)ws_size;
  const float* x    = (const float*)d_in[0];
  const float* h0   = (const float*)d_in[1];
  const float* w_ih = (const float*)d_in[2];
  const float* w_hh = (const float*)d_in[3];
  const float* b_ih = (const float*)d_in[4];
  const float* b_hh = (const float*)d_in[5];
  float* out = (float*)d_out;

  char* p = (char*)d_ws;
  __hip_bfloat16* SEQA = (__hip_bfloat16*)p; p += (size_t)16384 * 2048 * 2;   // 64 MiB
  __hip_bfloat16* SEQB = (__hip_bfloat16*)p; p += (size_t)16384 * 2048 * 2;   // 64 MiB
  float* GX            = (float*)p;          p += (size_t)2048 * 3072 * 4;    // 24 MiB
  __hip_bfloat16* Wihb = (__hip_bfloat16*)p; p += (size_t)6144 * 2048 * 2;    // 24 MiB
  __hip_bfloat16* Whhb = (__hip_bfloat16*)p; p += (size_t)6144 * 1024 * 2;    // 12 MiB
  __hip_bfloat16* HB   = (__hip_bfloat16*)p; p += (size_t)2 * 131072 * 2;     // 512 KiB
  float* HF            = (float*)p;          p += (size_t)2 * 131072 * 4;     // 1 MiB

  f2b<<<2048, 256, 0, stream>>>(x, SEQA, 16384 * 2048);

  for (int l = 0; l < 3; ++l) {
    const __hip_bfloat16* In = (l & 1) ? SEQB : SEQA;
    __hip_bfloat16* Yout = (l & 1) ? SEQA : SEQB;   // unused for l==2
    const int writeY = (l < 2) ? 1 : 0;

    f2b<<<2048, 256, 0, stream>>>(w_ih + (size_t)l * 6144 * 2048, Wihb, 6144 * 2048);
    f2b<<<2048, 256, 0, stream>>>(w_hh + (size_t)l * 6144 * 1024, Whhb, 6144 * 1024);
    f2b<<<64, 256, 0, stream>>>(h0 + (size_t)l * 131072, HB, 131072);

    for (int ph = 0; ph < 16; ++ph) {
      const int rowBase0 = ph * 1024;            // fwd t in [16p, 16p+16)
      const int rowBase1 = 15360 - ph * 1024;    // bwd tau in [240-16p, 256-16p)
      gemm_bias_bt<<<dim3(16, 24), 256, 0, stream>>>(
          In, Wihb, b_ih + l * 6144, GX, rowBase0, rowBase1);

      for (int u = 0; u < 16; ++u) {
        const int t = ph * 16 + u;
        const int gxFwd = u * 64;
        const int gxBwd = 1024 + (15 - u) * 64;
        const float* hf_in = (t == 0) ? (h0 + (size_t)l * 131072) : (HF + (size_t)(t & 1) * 131072);
        float* hf_out = HF + (size_t)((t + 1) & 1) * 131072;
        const __hip_bfloat16* hb_in = HB + (size_t)(t & 1) * 131072;
        __hip_bfloat16* hb_out = HB + (size_t)((t + 1) & 1) * 131072;
        gru_step<<<256, 256, 0, stream>>>(
            Whhb, b_hh + l * 6144, GX,
            hb_in, hf_in, hb_out, hf_out, Yout,
            out + (size_t)l * 131072, t, gxFwd, gxBwd, writeY, (t == 255) ? 1 : 0);
      }
    }
  }
}